// Round 12
// baseline (252.668 us; speedup 1.0000x reference)
//
#include <hip/hip_runtime.h>
#include <float.h>

#define KTOP 32
#define BCAP 512               // bucket capacity (pre-cmask E[373] @ thr2.0, ~7 sigma)
#define SENT_U32 0xFF7F0000u   // bf16-rounds to largest finite negative
#define VCLAMP 3.0e38f
#define STHRESH 2.0f           // P(s>=2.0)=2.28%; pre-cmask E=373, post E=187
#define OVERMARK 0x7FFFFFFF

__device__ __forceinline__ unsigned int f2u(float f){
  unsigned int u = __float_as_uint(f);
  return (u & 0x80000000u) ? ~u : (u | 0x80000000u);
}

// ---- cooperative segment-bounds search (proven r9/r11). TPB = 2*HALF, HALF=1<<LOG.
template<int LOG>
__device__ void seg_bounds(const int* __restrict__ batch, int E, int g,
                           int* srch, int* sbounds){
  const int HALF = 1 << LOG;
  int tid = threadIdx.x;
  int grp = (tid >= HALF) ? 1 : 0;
  int lt  = tid - grp * HALF;
  int target = g + grp;
  int lo = 0, hi = E;                 // invariant: batch[lo-1] < target <= batch[hi]
  for (int round = 0; round < 4; ++round){
    if (lt == 0) srch[grp] = 0;
    __syncthreads();
    int width = hi - lo;
    int pred = 0;
    if (width > HALF){
      long long w = width;
      int q = lo + (int)((w * (long long)lt) >> LOG);   // q_0 = lo, all q < hi
      pred = (batch[q] < target) ? 1 : 0;
    }
    unsigned long long bal = __ballot(pred);
    if ((tid & 63) == 0) atomicAdd(&srch[grp], __popcll(bal));
    __syncthreads();
    if (width > HALF){
      long long w = width;
      int c = srch[grp];              // preds are a prefix (batch sorted)
      int nlo = (c > 0)    ? lo + (int)((w * (long long)(c - 1)) >> LOG) + 1 : lo;
      int nhi = (c < HALF) ? lo + (int)((w * (long long)c) >> LOG)           : hi;
      lo = nlo; hi = nhi;
    }
    __syncthreads();
  }
  if (lt == 0) srch[grp] = 0;
  __syncthreads();
  int width = hi - lo;                // <= HALF after 4 rounds for any E < 2^31
  int pred = (lt < width) ? ((batch[lo + lt] < target) ? 1 : 0) : 0;
  unsigned long long bal = __ballot(pred);
  if ((tid & 63) == 0) atomicAdd(&srch[grp], __popcll(bal));
  __syncthreads();
  if (lt == 0) sbounds[grp] = lo + srch[grp];
  __syncthreads();
}

// =================== K1: per-segment score stream -> bucket in out[s..] ===================
// r10's proven-fast k_scan shape; bucket lives in the segment's OWN slice of out.
__global__ void __launch_bounds__(512, 4)
k_scan(const float* __restrict__ scores, const int* __restrict__ batch,
       float* __restrict__ out, int E, int NG)
{
  __shared__ unsigned int st_u[BCAP];
  __shared__ int st_i[BCAP];
  __shared__ int srch[2], sbounds[2];
  __shared__ int scnt;
  int tid = threadIdx.x, g = blockIdx.x;
  if (tid == 0) scnt = 0;
  seg_bounds<8>(batch, E, g, srch, sbounds);
  int s = sbounds[0], e = sbounds[1];
  if (e <= s) return;                 // empty segment: K2/K3 skip it too

  int s4 = (s + 3) & ~3; if (s4 > e) s4 = e;
  int e4 = e & ~3;       if (e4 < s4) e4 = s4;
  const float4* sc4 = (const float4*)scores;

  auto proc4 = [&](float4 a, int bidx){
    int h = (a.x >= STHRESH ? 1 : 0) | (a.y >= STHRESH ? 2 : 0)
          | (a.z >= STHRESH ? 4 : 0) | (a.w >= STHRESH ? 8 : 0);
    if (h){
      int sl = atomicAdd(&scnt, __popc(h));
      if (h & 1){ if (sl < BCAP){ st_u[sl] = f2u(a.x); st_i[sl] = bidx;     } sl++; }
      if (h & 2){ if (sl < BCAP){ st_u[sl] = f2u(a.y); st_i[sl] = bidx + 1; } sl++; }
      if (h & 4){ if (sl < BCAP){ st_u[sl] = f2u(a.z); st_i[sl] = bidx + 2; } sl++; }
      if (h & 8){ if (sl < BCAP){ st_u[sl] = f2u(a.w); st_i[sl] = bidx + 3; } }
    }
  };
  auto st1 = [&](float sc, int idx){
    if (sc >= STHRESH){
      int sl = atomicAdd(&scnt, 1);
      if (sl < BCAP){ st_u[sl] = f2u(sc); st_i[sl] = idx; }
    }
  };
  {
    int i = s + tid;  if (i < s4) st1(scores[i], i);
    int j = e4 + tid; if (j < e)  st1(scores[j], j);
    int q  = (s4 >> 2) + tid;
    int qe = (e4 >> 2);
    for (; q + 3 * 512 < qe; q += 4 * 512){
      float4 a0 = sc4[q];
      float4 a1 = sc4[q +     512];
      float4 a2 = sc4[q + 2 * 512];
      float4 a3 = sc4[q + 3 * 512];
      proc4(a0, q << 2);
      proc4(a1, (q +     512) << 2);
      proc4(a2, (q + 2 * 512) << 2);
      proc4(a3, (q + 3 * 512) << 2);
    }
    for (; q < qe; q += 512){
      float4 a = sc4[q];
      proc4(a, q << 2);
    }
  }
  __syncthreads();
  int n = scnt;
  int cap = (e - s - 1) >> 1;                     // pairs that fit in the slice
  bool over = (n > BCAP) || (n > cap);
  int* outw = (int*)out;
  if (tid == 0) outw[s] = over ? OVERMARK : n;    // count word (OVER -> K2 fallback)
  if (!over){
    for (int t = tid; t < n; t += 512){
      outw[s + 1 + 2 * t] = (int)st_u[t];
      outw[s + 2 + 2 * t] = st_i[t];
    }
  }
}

// ---------------- fallback helpers (exact radix select, 256-thread) ----------------
__device__ int suffix_total(int* hist, int NB, int* gsum, int tid){
  int GS = NB >> 8;
  if (tid < 256){
    int p = 0, base = tid * GS;
    for (int j = 0; j < GS; ++j) p += hist[base + j];
    gsum[tid] = p;
  }
  __syncthreads();
  for (int d = 1; d < 256; d <<= 1){
    int v = 0;
    if (tid < 256) v = (tid + d < 256) ? gsum[tid + d] : 0;
    __syncthreads();
    if (tid < 256) gsum[tid] += v;
    __syncthreads();
  }
  return gsum[0];
}

__device__ int find_bin(int* hist, int NB, int* gsum, int R, int* s2, int tid,
                        int* above_out){
  int GS = NB >> 8;
  if (tid < 256){
    int St  = gsum[tid];
    int St1 = (tid < 255) ? gsum[tid + 1] : 0;
    if (R > St1 && R <= St) s2[0] = tid;
  }
  __syncthreads();
  if (tid == 0){
    int G = s2[0];
    int above = (G < 255) ? gsum[G + 1] : 0;
    int b = (G + 1) * GS - 1;
    for (; b > G * GS; --b){
      int h = hist[b];
      if (above + h >= R) break;
      above += h;
    }
    s2[0] = b; s2[1] = above;
  }
  __syncthreads();
  int bin = s2[0];
  *above_out = s2[1];
  __syncthreads();
  return bin;
}

// =================== K2: bucket -> cmask -> rank -> LSE -> compact in out[s..] ===================
__global__ void __launch_bounds__(256)
k_select(const float* __restrict__ logits,
         const float* __restrict__ scores,
         const float* __restrict__ stop_logits,
         const int* __restrict__ batch,
         const int* __restrict__ cmask,
         float* __restrict__ out, int E, int NG)
{
  __shared__ unsigned int bin_u[BCAP];
  __shared__ int          bin_i[BCAP];
  __shared__ unsigned int sv_u[BCAP];
  __shared__ int          sv_i[BCAP];
  __shared__ int hist[2048];          // fallback only
  __shared__ int gsum[256];
  __shared__ int s2[2];
  __shared__ int srch[2], sbounds[2];
  __shared__ int ab_i[KTOP];
  __shared__ int vidx[KTOP];
  __shared__ float vlog[KTOP];
  __shared__ int cnt2, fcnt, cnt_ab, vcnt;
  __shared__ float sh_logden;

  int tid = threadIdx.x, g = blockIdx.x;
  if (tid == 0){ cnt2 = 0; fcnt = 0; cnt_ab = 0; vcnt = 0; }
  seg_bounds<7>(batch, E, g, srch, sbounds);
  int s = sbounds[0], e = sbounds[1], len = e - s;
  if (len == 0) return;
  int* outw = (int*)out;
  const float4* sc4 = (const float4*)scores;

  if (len < 2 * KTOP + 1){
    // ---- tiny segment (<65): finalize whole segment right here (wave 0) ----
    if (tid < 64){
      float sc = 0.f; int cm = 0; float lg = 0.f;
      if (tid < len){ sc = scores[s + tid]; cm = cmask[s + tid]; lg = logits[s + tid]; }
      bool cand = (tid < len) && (cm != 0);
      unsigned key = cand ? f2u(sc) : 0u;
      unsigned long long kj = ((unsigned long long)key << 32)
                            | (unsigned)(~(unsigned)(s + tid));
      int rank = 0;
      for (int k = 0; k < 64; ++k){
        unsigned ok = __shfl(key, k);
        int oc = __shfl(cand ? 1 : 0, k);
        unsigned long long kk = ((unsigned long long)ok << 32)
                              | (unsigned)(~(unsigned)(s + k));
        rank += (oc && kk > kj) ? 1 : 0;
      }
      bool valid = cand && (rank < KTOP);
      float v = valid ? lg : -FLT_MAX;
      float m = v;
      #pragma unroll
      for (int d = 32; d; d >>= 1) m = fmaxf(m, __shfl_xor(m, d));
      float ex = valid ? expf(v - m) : 0.f;
      #pragma unroll
      for (int d = 32; d; d >>= 1) ex += __shfl_xor(ex, d);
      unsigned long long vb = __ballot(valid);
      float logden = 0.f;
      if (tid == 0){
        float stop = stop_logits[g];
        if (vb == 0ull) logden = stop;
        else {
          float lse = logf(fmaxf(ex, FLT_EPSILON)) + m;
          float mx = fmaxf(lse, stop);
          float dd = fabsf(lse - stop);
          logden = mx + log1pf(expf(-dd));
        }
      }
      logden = __shfl(logden, 0);
      if (tid < len){
        float ov;
        if (valid){
          float val = lg - logden;
          if (!(val >= -VCLAMP)) val = -VCLAMP;
          if (val > VCLAMP)      val =  VCLAMP;
          ov = val;
        } else ov = __uint_as_float(SENT_U32);
        out[s + tid] = ov;
      }
    }
    return;                           // K3 skips len<65
  }

  int n = outw[s];
  bool over = ((unsigned)n > (unsigned)BCAP);     // catches OVERMARK too
  if (!over){
    for (int t = tid; t < n; t += 256){
      bin_u[t] = (unsigned)outw[s + 1 + 2 * t];
      bin_i[t] = outw[s + 2 + 2 * t];
    }
  }
  __syncthreads();
  if (!over){
    // batched scattered cmask resolve
    for (int t = tid; t < n; t += 256){
      int idx = bin_i[t];
      if (cmask[idx]){
        int sl = atomicAdd(&cnt2, 1);
        sv_u[sl] = bin_u[t]; sv_i[sl] = idx;      // sl < n <= BCAP
      }
    }
  }
  __syncthreads();
  int S = cnt2;

  if (!over && S >= KTOP){
    // ---- FAST PATH (exact): top-32 subset of survivors; tie-break (u desc, idx asc)
    for (int jj = tid; jj < S; jj += 256){
      unsigned long long kj = ((unsigned long long)sv_u[jj] << 32)
                            | (unsigned long long)(unsigned)(~(unsigned)sv_i[jj]);
      int rank = 0;
      for (int k = 0; k < S; ++k){
        unsigned long long kk = ((unsigned long long)sv_u[k] << 32)
                              | (unsigned long long)(unsigned)(~(unsigned)sv_i[k]);
        rank += (kk > kj) ? 1 : 0;
      }
      if (rank < KTOP){
        int sl = atomicAdd(&vcnt, 1);
        if (sl < KTOP) vidx[sl] = sv_i[jj];
      }
    }
  } else {
    // ---- FALLBACK (exact, rare): full radix with dense rescan of [s,e) ----
    int s4 = (s + 3) & ~3; if (s4 > e) s4 = e;
    int e4 = e & ~3;       if (e4 < s4) e4 = s4;
    auto scan_sc = [&](auto&& fn){
      int i = s + tid;  if (i < s4) fn(scores[i], i);
      int j = e4 + tid; if (j < e)  fn(scores[j], j);
      for (int q = (s4 >> 2) + tid, qe = (e4 >> 2); q < qe; q += 256){
        float4 sc = sc4[q];
        int base = q << 2;
        fn(sc.x, base);     fn(sc.y, base + 1);
        fn(sc.z, base + 2); fn(sc.w, base + 3);
      }
    };
    auto is_cand = [&](int idx) -> bool { return cmask[idx] != 0; };

    for (int b = tid; b < 2048; b += 256) hist[b] = 0;
    if (tid == 0){ fcnt = 0; cnt_ab = 0; }
    __syncthreads();
    scan_sc([&](float sc, int idx){
      if (is_cand(idx)) atomicAdd(&hist[f2u(sc) >> 21], 1);
    });
    __syncthreads();
    int T = suffix_total(hist, 2048, gsum, tid);
    bool sel = (T > KTOP);
    unsigned int prefix = 0; int pshift = 32; int R = KTOP;
    if (sel){
      int above;
      int b1 = find_bin(hist, 2048, gsum, R, s2, tid, &above);
      R -= above; prefix = (unsigned)b1; pshift = 21;
      int hcnt = hist[b1];
      __syncthreads();
      if (hcnt > BCAP){                       // refine bits [20:10]
        for (int b = tid; b < 2048; b += 256) hist[b] = 0;
        __syncthreads();
        scan_sc([&](float sc, int idx){
          unsigned u = f2u(sc);
          if ((u >> 21) == prefix && is_cand(idx))
            atomicAdd(&hist[(u >> 10) & 0x7FFu], 1);
        });
        __syncthreads();
        suffix_total(hist, 2048, gsum, tid);
        int b2 = find_bin(hist, 2048, gsum, R, s2, tid, &above);
        R -= above; prefix = (prefix << 11) | (unsigned)b2; pshift = 10;
        hcnt = hist[b2];
        __syncthreads();
        if (hcnt > BCAP){                     // final bits [9:0]
          for (int b = tid; b < 1024; b += 256) hist[b] = 0;
          __syncthreads();
          scan_sc([&](float sc, int idx){
            unsigned u = f2u(sc);
            if ((u >> 10) == prefix && is_cand(idx))
              atomicAdd(&hist[u & 0x3FFu], 1);
          });
          __syncthreads();
          suffix_total(hist, 1024, gsum, tid);
          int b3 = find_bin(hist, 1024, gsum, R, s2, tid, &above);
          R -= above; prefix = (prefix << 10) | (unsigned)b3; pshift = 0;
          __syncthreads();
        }
      }
      scan_sc([&](float sc, int idx){
        unsigned u = f2u(sc);
        unsigned hp = (pshift < 32) ? (u >> pshift) : 0u;
        if (hp >= prefix){
          if (is_cand(idx)){
            if (hp == prefix){
              int sl = atomicAdd(&fcnt, 1);
              if (sl < BCAP){ bin_u[sl] = u; bin_i[sl] = idx; }
            } else {
              int sl = atomicAdd(&cnt_ab, 1);
              if (sl < KTOP) ab_i[sl] = idx;  // strictly-above count < R <= 32
            }
          }
        }
      });
      __syncthreads();
      int bn = min(fcnt, BCAP);
      for (int jj = tid; jj < bn; jj += 256){
        unsigned long long kj = ((unsigned long long)bin_u[jj] << 32)
                              | (unsigned long long)(unsigned)(~(unsigned)bin_i[jj]);
        int rank = 0;
        for (int k = 0; k < bn; ++k){
          unsigned long long kk2 = ((unsigned long long)bin_u[k] << 32)
                                 | (unsigned long long)(unsigned)(~(unsigned)bin_i[k]);
          rank += (kk2 > kj) ? 1 : 0;
        }
        if (rank < R){
          int sl = atomicAdd(&vcnt, 1);
          if (sl < KTOP) vidx[sl] = bin_i[jj];
        }
      }
      int na = min(cnt_ab, KTOP);
      for (int jj = tid; jj < na; jj += 256){
        int sl = atomicAdd(&vcnt, 1);
        if (sl < KTOP) vidx[sl] = ab_i[jj];
      }
    } else {
      // T <= 32: every candidate is valid
      scan_sc([&](float sc, int idx){
        (void)sc;
        if (is_cand(idx)){
          int sl = atomicAdd(&vcnt, 1);
          if (sl < KTOP) vidx[sl] = idx;
        }
      });
    }
  }
  __syncthreads();

  // ---- LSE over the <=32 valid logits (wave 0) ----
  int c = min(vcnt, KTOP);
  if (tid < c) vlog[tid] = logits[vidx[tid]];
  __syncthreads();
  if (tid < 64){
    float v = (tid < c) ? vlog[tid] : -FLT_MAX;
    float m = v;
    #pragma unroll
    for (int d = 32; d; d >>= 1) m = fmaxf(m, __shfl_xor(m, d));
    float ex = (tid < c) ? expf(v - m) : 0.f;
    #pragma unroll
    for (int d = 32; d; d >>= 1) ex += __shfl_xor(ex, d);
    if (tid == 0){
      float stop = stop_logits[g];              // TEMP == 1.0
      float logden;
      if (c == 0){
        logden = stop;
      } else {
        float lse = logf(fmaxf(ex, FLT_EPSILON)) + m;   // eps clamp per reference
        float mx = fmaxf(lse, stop);
        float dd = fabsf(lse - stop);
        logden = mx + log1pf(expf(-dd));
      }
      sh_logden = logden;
    }
  }
  __syncthreads();

  // ---- compact result into own prefix: count + (idx, final_val) pairs ----
  if (tid == 0) outw[s] = c;                    // 0..32
  if (tid < c){
    float val = vlog[tid] - sh_logden;
    if (!(val >= -VCLAMP)) val = -VCLAMP;       // flushes NaN too
    if (val > VCLAMP)      val =  VCLAMP;
    outw[s + 1 + 2 * tid] = vidx[tid];
    outw[s + 2 + 2 * tid] = __float_as_int(val);
  }
}

// =================== K3: read compact, sentinel-fill own segment, scatter ===================
__global__ void __launch_bounds__(256)
k_finish(const int* __restrict__ batch, float* __restrict__ out, int E, int NG)
{
  __shared__ int srch[2], sbounds[2];
  __shared__ int c_sh;
  __shared__ int idxs[KTOP];
  __shared__ int vals[KTOP];
  int tid = threadIdx.x, g = blockIdx.x;
  seg_bounds<7>(batch, E, g, srch, sbounds);
  int s = sbounds[0], e = sbounds[1], len = e - s;
  if (len < 2 * KTOP + 1) return;     // K2 finalized tiny segments (incl. len==0)
  int* outw = (int*)out;
  if (tid == 0) c_sh = outw[s];
  __syncthreads();
  int c = c_sh; if (c < 0) c = 0; if (c > KTOP) c = KTOP;
  if (tid < c){ idxs[tid] = outw[s + 1 + 2 * tid]; vals[tid] = outw[s + 2 + 2 * tid]; }
  __syncthreads();                    // reads done before fill overwrites prefix

  const float SENT = __uint_as_float(SENT_U32);
  const float4 sv = make_float4(SENT, SENT, SENT, SENT);
  float4* out4 = (float4*)out;
  int s4 = (s + 3) & ~3; if (s4 > e) s4 = e;
  int e4 = e & ~3;       if (e4 < s4) e4 = s4;
  int i = s + tid;  if (i < s4) out[i] = SENT;
  int j = e4 + tid; if (j < e)  out[j] = SENT;
  for (int q = (s4 >> 2) + tid, qe = (e4 >> 2); q < qe; q += 256)
    out4[q] = sv;
  __syncthreads();                    // fill done before scatter
  if (tid < c) out[idxs[tid]] = __int_as_float(vals[tid]);
}

extern "C" void kernel_launch(void* const* d_in, const int* in_sizes, int n_in,
                              void* d_out, int out_size, void* d_ws, size_t ws_size,
                              hipStream_t stream){
  const float* edge_logits = (const float*)d_in[0];
  const float* edge_scores = (const float*)d_in[1];
  const float* stop_logits = (const float*)d_in[2];
  const int*   edge_batch  = (const int*)d_in[3];
  const int*   cmask       = (const int*)d_in[4];
  int E  = in_sizes[0];
  int NG = in_sizes[2];
  float* out = (float*)d_out;
  (void)d_ws; (void)ws_size;   // ws use triggers a ~41us 268MB poison fill — never touch it

  hipLaunchKernelGGL(k_scan,   dim3(NG), dim3(512), 0, stream,
                     edge_scores, edge_batch, out, E, NG);
  hipLaunchKernelGGL(k_select, dim3(NG), dim3(256), 0, stream,
                     edge_logits, edge_scores, stop_logits, edge_batch, cmask,
                     out, E, NG);
  hipLaunchKernelGGL(k_finish, dim3(NG), dim3(256), 0, stream,
                     edge_batch, out, E, NG);
}